// Round 21
// baseline (189.807 us; speedup 1.0000x reference)
//
#include <hip/hip_runtime.h>
#include <math.h>

typedef __bf16 bf16x8 __attribute__((ext_vector_type(8)));
typedef float f32x4 __attribute__((ext_vector_type(4)));
typedef unsigned short ushort8 __attribute__((ext_vector_type(8)));

__device__ __forceinline__ float bf2f(unsigned short u){ return __uint_as_float(((unsigned)u) << 16); }
__device__ __forceinline__ unsigned short f2bf(float f){
  unsigned v = __float_as_uint(f);
  return (unsigned short)((v + 0x7FFFu + ((v >> 16) & 1u)) >> 16);
}

// ---------- pack W1 [128][2][3][3] -> A-frag order [ct=8][lane=64][8], k = ci*9+dhw, pad k>=18 ----------
__global__ void packw1_kernel(const float* __restrict__ W1, unsigned short* __restrict__ Wpk1)
{
  int idx = blockIdx.x*256 + threadIdx.x;   // 512 total
  if (idx >= 512) return;
  int lane = idx & 63, ct = idx >> 6;
  int co = ct*16 + (lane & 15);
  int lq = lane >> 4;
#pragma unroll
  for (int j = 0; j < 8; ++j){
    int k = lq*8 + j;
    Wpk1[(size_t)idx*8 + j] = (k < 18) ? f2bf(W1[(size_t)co*18 + k]) : (unsigned short)0;
  }
}

// ================= conv1: 2->128 via single-K MFMA, fused stats =================
__global__ __launch_bounds__(256, 2) void conv1_mfma(
    const float* __restrict__ F, const unsigned short* __restrict__ Wpk1,
    const float* __restrict__ b1, unsigned short* __restrict__ y1,
    float* __restrict__ stats)
{
  __shared__ float xp[2*484];
  __shared__ float sred[256];
  const int tid = threadIdx.x, b = blockIdx.x;
  const int wid = tid >> 6, lane = tid & 63, lq = lane >> 4, lr = lane & 15;

  for (int i = tid; i < 256; i += 256) sred[i] = 0.f;
  for (int i = tid; i < 968; i += 256) xp[i] = 0.f;
  __syncthreads();
  for (int i = tid; i < 800; i += 256){
    int ci = i / 400, p = i - ci*400;
    xp[ci*484 + (p/20 + 1)*22 + (p%20) + 1] = F[((size_t)b*2 + ci)*400 + p];
  }
  __syncthreads();

  bf16x8 af[8];
#pragma unroll
  for (int ct = 0; ct < 8; ++ct)
    af[ct] = *(const bf16x8*)(Wpk1 + (size_t)(ct*64 + lane)*8);

  int off[8]; bool kval[8];
#pragma unroll
  for (int j = 0; j < 8; ++j){
    int k = lq*8 + j;
    kval[j] = (k < 18);
    int kc = kval[j] ? k : 0;
    int ci = kc / 9, dhw = kc - ci*9;
    off[j] = ci*484 + (dhw/3)*22 + (dhw - (dhw/3)*3);
  }

  f32x4 bias[8];
#pragma unroll
  for (int ct = 0; ct < 8; ++ct)
    bias[ct] = *(const f32x4*)(b1 + ct*16 + lq*4);

  float smv[8][4], sqv[8][4];
#pragma unroll
  for (int ct = 0; ct < 8; ++ct)
#pragma unroll
    for (int r = 0; r < 4; ++r){ smv[ct][r] = 0.f; sqv[ct][r] = 0.f; }

  for (int pt = wid; pt < 25; pt += 4){
    const int px = pt*16 + lr;
    const int h = px/20, w = px - (px/20)*20;
    const int base = h*22 + w;
    union { unsigned short u[8]; bf16x8 h8; } bfr;
#pragma unroll
    for (int j = 0; j < 8; ++j){
      float xv = kval[j] ? xp[base + off[j]] : 0.f;
      bfr.u[j] = f2bf(xv);
    }
    f32x4 zero4 = {0.f,0.f,0.f,0.f};
#pragma unroll
    for (int ct = 0; ct < 8; ++ct){
      f32x4 acc = __builtin_amdgcn_mfma_f32_16x16x32_bf16(af[ct], bfr.h8, zero4, 0, 0, 0);
      f32x4 y = acc + bias[ct];
      union { unsigned short u[4]; unsigned long long ll; } pk;
#pragma unroll
      for (int r = 0; r < 4; ++r){
        pk.u[r] = f2bf(y[r]);
        smv[ct][r] += y[r];
        sqv[ct][r] = fmaf(y[r], y[r], sqv[ct][r]);
      }
      *(unsigned long long*)(y1 + ((size_t)b*400 + px)*128 + ct*16 + lq*4) = pk.ll;
    }
  }

#pragma unroll
  for (int ct = 0; ct < 8; ++ct)
#pragma unroll
    for (int r = 0; r < 4; ++r){
      float v = smv[ct][r], q = sqv[ct][r];
#pragma unroll
      for (int m = 1; m < 16; m <<= 1){ v += __shfl_xor(v, m); q += __shfl_xor(q, m); }
      if (lr == 0){
        int co = ct*16 + lq*4 + r;
        atomicAdd(&sred[co], v);
        atomicAdd(&sred[128 + co], q);
      }
    }
  __syncthreads();
  float* st = stats + (size_t)(b & 3) * 256;
  for (int i = tid; i < 256; i += 256)
    atomicAdd(&st[i], sred[i]);
}

// ---------- fold sliced stats -> per-channel scale/shift ----------
__global__ void bn_fin(const float* __restrict__ stats, const float* __restrict__ g,
                       const float* __restrict__ be, float* __restrict__ ss,
                       int C, float invN, int nsl)
{
  int c = threadIdx.x;
  if (c < C){
    float s = 0.f, q = 0.f;
    for (int t = 0; t < nsl; ++t){ s += stats[t*2*C + c]; q += stats[t*2*C + C + c]; }
    float mean = s * invN;
    float var  = q * invN - mean * mean;
    float sc   = g[c] * rsqrtf(var + 1e-5f);
    ss[c]      = sc;
    ss[C + c]  = be[c] - mean * sc;
  }
}

// ---------- weight pack, PASS-MAJOR ----------
__global__ void packw_kernel(const float* __restrict__ W, unsigned short* __restrict__ Wpk,
                             int CT, int CIN, int total)
{
  int idx = blockIdx.x*256 + threadIdx.x;
  if (idx >= total) return;
  int lane = idx & 63;
  int t2 = idx >> 6;
  int dhw = t2 % 9;
  int t3 = t2 / 9;
  int ct = t3 % CT;
  int p  = t3 / CT;
  int co = ct*16 + (lane & 15);
  int ci0 = p*32 + (lane >> 4)*8;
#pragma unroll
  for (int j = 0; j < 8; ++j)
    Wpk[(size_t)idx*8 + j] = f2bf(W[((size_t)co*CIN + ci0 + j)*9 + dhw]);
}

// ===== MFMA implicit-GEMM conv 3x3 SAME (v13: v11 + coalesced two-phase C-write) =====
template<int CIN, int COUT>
__global__ __launch_bounds__(512, 4) void conv_mfma(
    const unsigned short* __restrict__ xin, const float* __restrict__ ss_in,
    const unsigned short* __restrict__ Wpk, const float* __restrict__ bconv,
    unsigned short* __restrict__ yout, float* __restrict__ stats)
{
  constexpr int NCC = CIN/32;
  constexpr int CT  = COUT/16;
  constexpr int WCH = CT*9*64;
  __shared__ unsigned short xs[484*5*8];
  __shared__ unsigned short wl[WCH*8];
  __shared__ float sred[2*COUT];

  const int tid = threadIdx.x, b = blockIdx.x;
  const int wid = tid >> 6, lane = tid & 63, lq = lane >> 4, lr = lane & 15;
  const int oct = tid & 3;

  for (int i = tid; i < 2*COUT; i += 512) sred[i] = 0.f;

  int pp[4];
#pragma unroll
  for (int s = 0; s < 4; ++s){
    int tile = (s < 3) ? (wid + 8*s) : 24;
    int px = tile*16 + lr;
    int prow = px/20, pcol = px - prow*20;
    pp[s] = (prow + 1)*22 + (pcol + 1);
  }

  f32x4 acc[CT][4];
#pragma unroll
  for (int ct = 0; ct < CT; ++ct)
#pragma unroll
    for (int s = 0; s < 4; ++s){ acc[ct][s][0]=0.f; acc[ct][s][1]=0.f; acc[ct][s][2]=0.f; acc[ct][s][3]=0.f; }

  for (int p = 0; p < NCC; ++p){
    __syncthreads();
    for (int i = tid; i < WCH; i += 512)
      *(uint4*)&wl[(size_t)i*8] = *(const uint4*)(Wpk + ((size_t)p*WCH + i)*8);
    {
      const int c = p*32 + oct*8;
      f32x4 s0 = *(const f32x4*)(ss_in + c);
      f32x4 s1 = *(const f32x4*)(ss_in + c + 4);
      f32x4 h0 = *(const f32x4*)(ss_in + CIN + c);
      f32x4 h1 = *(const f32x4*)(ss_in + CIN + c + 4);
      for (int i = tid; i < 484*4; i += 512){
        int pidx = i >> 2;
        int r22 = pidx/22, c22 = pidx - r22*22;
        int row = r22 - 1, col = c22 - 1;
        union { unsigned short u[8]; uint4 v; } pk;
        if ((unsigned)row < 20u && (unsigned)col < 20u){
          ushort8 raw = *(const ushort8*)(xin + ((size_t)b*400 + row*20 + col)*CIN + c);
          pk.u[0] = f2bf(fmaxf(fmaf(bf2f(raw[0]), s0[0], h0[0]), 0.f));
          pk.u[1] = f2bf(fmaxf(fmaf(bf2f(raw[1]), s0[1], h0[1]), 0.f));
          pk.u[2] = f2bf(fmaxf(fmaf(bf2f(raw[2]), s0[2], h0[2]), 0.f));
          pk.u[3] = f2bf(fmaxf(fmaf(bf2f(raw[3]), s0[3], h0[3]), 0.f));
          pk.u[4] = f2bf(fmaxf(fmaf(bf2f(raw[4]), s1[0], h1[0]), 0.f));
          pk.u[5] = f2bf(fmaxf(fmaf(bf2f(raw[5]), s1[1], h1[1]), 0.f));
          pk.u[6] = f2bf(fmaxf(fmaf(bf2f(raw[6]), s1[2], h1[2]), 0.f));
          pk.u[7] = f2bf(fmaxf(fmaf(bf2f(raw[7]), s1[3], h1[3]), 0.f));
        } else {
          pk.v.x = 0u; pk.v.y = 0u; pk.v.z = 0u; pk.v.w = 0u;
        }
        *(uint4*)&xs[(size_t)(pidx*5 + oct)*8] = pk.v;
      }
    }
    __syncthreads();

#pragma unroll
    for (int dhw = 0; dhw < 9; ++dhw){
      const int doff = (dhw/3 - 1)*22 + (dhw - (dhw/3)*3 - 1);
      bf16x8 af[CT];
#pragma unroll
      for (int ct = 0; ct < CT; ++ct)
        af[ct] = *(const bf16x8*)&wl[(size_t)((ct*9 + dhw)*64 + lane)*8];
#pragma unroll
      for (int s = 0; s < 4; ++s){
        if (s == 3 && wid != 0) continue;   // wave-uniform: only wave 0 owns tile 24
        bf16x8 bf = *(const bf16x8*)&xs[(size_t)((pp[s] + doff)*5 + lq)*8];
#pragma unroll
        for (int ct = 0; ct < CT; ++ct)
          acc[ct][s] = __builtin_amdgcn_mfma_f32_16x16x32_bf16(af[ct], bf, acc[ct][s], 0, 0, 0);
      }
    }
  }

  // ---- stats (in-reg; no stores here) ----
  f32x4 biasv[CT];
#pragma unroll
  for (int ct = 0; ct < CT; ++ct) biasv[ct] = *(const f32x4*)(bconv + ct*16 + lq*4);

  float smv[CT][4], sqv[CT][4];
#pragma unroll
  for (int ct = 0; ct < CT; ++ct)
#pragma unroll
    for (int r = 0; r < 4; ++r){ smv[ct][r] = 0.f; sqv[ct][r] = 0.f; }

#pragma unroll
  for (int ct = 0; ct < CT; ++ct){
#pragma unroll
    for (int s = 0; s < 4; ++s){
      const bool valid = (s < 3) || (wid == 0);
      f32x4 y = acc[ct][s] + biasv[ct];
#pragma unroll
      for (int r = 0; r < 4; ++r){
        float yv = valid ? y[r] : 0.f;
        smv[ct][r] += yv;
        sqv[ct][r] = fmaf(yv, yv, sqv[ct][r]);
      }
    }
  }
#pragma unroll
  for (int ct = 0; ct < CT; ++ct)
#pragma unroll
    for (int r = 0; r < 4; ++r){
      float v = smv[ct][r], w2 = sqv[ct][r];
#pragma unroll
      for (int m = 1; m < 16; m <<= 1){ v += __shfl_xor(v, m); w2 += __shfl_xor(w2, m); }
      if (lr == 0){
        int co = ct*16 + lq*4 + r;
        atomicAdd(&sred[co], v);
        atomicAdd(&sred[COUT + co], w2);
      }
    }
  __syncthreads();   // sred complete; all compute reads of xs done
  {
    float* st = stats + (size_t)(b & 3) * 2 * COUT;
    for (int i = tid; i < 2*COUT; i += 512)
      atomicAdd(&st[i], sred[i]);
  }

  // ---- coalesced C-write: two px-phases through xs (reuse), 8B-slot XOR swizzle ----
  constexpr int SM  = COUT/4 - 1;  // slot mask (15 for COUT=64, 7 for 32)
  constexpr int CPX = COUT/8;      // 16B chunks per px

  auto WSTORE = [&](int s, int base){
    int tile = (s < 3) ? (wid + 8*s) : 24;
    int pxl = tile*16 + lr - base;
#pragma unroll
    for (int ct = 0; ct < CT; ++ct){
      f32x4 y = acc[ct][s] + biasv[ct];
      union { unsigned short u[4]; unsigned long long ll; } pk;
#pragma unroll
      for (int r = 0; r < 4; ++r) pk.u[r] = f2bf(y[r]);
      int slot = (ct*4 + lq) ^ (pxl & SM);
      *(unsigned long long*)&xs[(size_t)pxl*COUT + slot*4] = pk.ll;
    }
  };
  auto CSTORE = [&](int base, int pxn){
    const int cnt = pxn * CPX;
    unsigned short* dst = yout + ((size_t)b*400 + base)*COUT;
    for (int i = tid; i < cnt; i += 512){
      int pxl = i / CPX, j = i - pxl*CPX;
      int m = pxl & SM;
      unsigned long long lo = *(unsigned long long*)&xs[(size_t)pxl*COUT + ((2*j)     ^ m)*4];
      unsigned long long hi = *(unsigned long long*)&xs[(size_t)pxl*COUT + ((2*j + 1) ^ m)*4];
      union { unsigned long long q[2]; uint4 v; } o; o.q[0] = lo; o.q[1] = hi;
      *(uint4*)&dst[(size_t)i*8] = o.v;
    }
  };

  // phase A: px 0..191 (tiles 0..11)
  WSTORE(0, 0);
  if (wid < 4) WSTORE(1, 0);
  __syncthreads();
  CSTORE(0, 192);
  __syncthreads();
  // phase B: px 192..399 (tiles 12..24)
  if (wid >= 4) WSTORE(1, 192);
  WSTORE(2, 192);
  if (wid == 0) WSTORE(3, 192);
  __syncthreads();
  CSTORE(192, 208);
}

// ---------- pack/permute Wo[j][c*400+p] -> Wob[j][p*32+c] bf16, rows 200..255 zero ----------
__global__ __launch_bounds__(256) void wopack_kernel(const float* __restrict__ Wo,
                                                     unsigned short* __restrict__ Wob)
{
  __shared__ float row[12800];
  const int j = blockIdx.x, tid = threadIdx.x;
  if (j < 200){
    const float4* src = (const float4*)(Wo + (size_t)j*12800);
    for (int i = tid; i < 3200; i += 256) ((float4*)row)[i] = src[i];
    __syncthreads();
    for (int ko = tid; ko < 1600; ko += 256){
      int p = ko >> 2, c0 = (ko & 3)*8;
      union { unsigned short u[8]; uint4 v; } pk;
#pragma unroll
      for (int t = 0; t < 8; ++t) pk.u[t] = f2bf(row[(c0+t)*400 + p]);
      *(uint4*)(Wob + (size_t)j*12800 + ko*8) = pk.v;
    }
  } else {
    uint4 z = {0,0,0,0};
    for (int ko = tid; ko < 1600; ko += 256)
      *(uint4*)(Wob + (size_t)j*12800 + ko*8) = z;
  }
}

// ================= linear: MFMA split-K, BN+ReLU(y4) fused into A-stage =================
__global__ __launch_bounds__(256, 4) void linear_mfma(
    const unsigned short* __restrict__ y4, const float* __restrict__ ss4,
    const unsigned short* __restrict__ Wob, float* __restrict__ lin_z)
{
  __shared__ unsigned short As[64*128];
  __shared__ unsigned short Bs[64*128];
  const int tid = threadIdx.x;
  const int m0 = blockIdx.x * 64;
  const int j0 = blockIdx.y * 64;
  const int z  = blockIdx.z;
  const int wid = tid >> 6, lane = tid & 63, lq = lane >> 4, lr = lane & 15;
  const int srow = tid >> 4, soct = tid & 15;
  const int c0 = (soct & 3) * 8;

  f32x4 s0 = *(const f32x4*)(ss4 + c0);
  f32x4 s1 = *(const f32x4*)(ss4 + c0 + 4);
  f32x4 h0 = *(const f32x4*)(ss4 + 32 + c0);
  f32x4 h1 = *(const f32x4*)(ss4 + 32 + c0 + 4);

  f32x4 acc[4];
#pragma unroll
  for (int ct = 0; ct < 4; ++ct){ acc[ct][0]=0.f; acc[ct][1]=0.f; acc[ct][2]=0.f; acc[ct][3]=0.f; }

  for (int ch = 0; ch < 4; ++ch){
    const int k0 = z*512 + ch*128;
    __syncthreads();
#pragma unroll
    for (int pass = 0; pass < 4; ++pass){
      int row = pass*16 + srow;
      ushort8 raw = *(const ushort8*)(y4 + (size_t)(m0+row)*12800 + k0 + soct*8);
      union { unsigned short u[8]; uint4 v; } pk;
      pk.u[0] = f2bf(fmaxf(fmaf(bf2f(raw[0]), s0[0], h0[0]), 0.f));
      pk.u[1] = f2bf(fmaxf(fmaf(bf2f(raw[1]), s0[1], h0[1]), 0.f));
      pk.u[2] = f2bf(fmaxf(fmaf(bf2f(raw[2]), s0[2], h0[2]), 0.f));
      pk.u[3] = f2bf(fmaxf(fmaf(bf2f(raw[3]), s0[3], h0[3]), 0.f));
      pk.u[4] = f2bf(fmaxf(fmaf(bf2f(raw[4]), s1[0], h1[0]), 0.f));
      pk.u[5] = f2bf(fmaxf(fmaf(bf2f(raw[5]), s1[1], h1[1]), 0.f));
      pk.u[6] = f2bf(fmaxf(fmaf(bf2f(raw[6]), s1[2], h1[2]), 0.f));
      pk.u[7] = f2bf(fmaxf(fmaf(bf2f(raw[7]), s1[3], h1[3]), 0.f));
      *(uint4*)&As[(size_t)((row << 4) + (soct ^ (row & 7)))*8] = pk.v;
      uint4 wv = *(const uint4*)(Wob + (size_t)(j0+row)*12800 + k0 + soct*8);
      *(uint4*)&Bs[(size_t)((row << 4) + (soct ^ (row & 7)))*8] = wv;
    }
    __syncthreads();
#pragma unroll
    for (int ks = 0; ks < 4; ++ks){
      const int arow = wid*16 + lr;
      bf16x8 afr = *(const bf16x8*)&As[(size_t)((arow << 4) + ((ks*4 + lq) ^ (arow & 7)))*8];
#pragma unroll
      for (int ct = 0; ct < 4; ++ct){
        const int brow = ct*16 + lr;
        bf16x8 bfr = *(const bf16x8*)&Bs[(size_t)((brow << 4) + ((ks*4 + lq) ^ (brow & 7)))*8];
        acc[ct] = __builtin_amdgcn_mfma_f32_16x16x32_bf16(afr, bfr, acc[ct], 0, 0, 0);
      }
    }
  }
#pragma unroll
  for (int ct = 0; ct < 4; ++ct){
    int j = j0 + ct*16 + lr;
    if (j < 208){
#pragma unroll
      for (int r = 0; r < 4; ++r){
        int m = m0 + wid*16 + lq*4 + r;
        lin_z[((size_t)z*512 + m)*208 + j] = acc[ct][r];
      }
    }
  }
}

// ============ phase v3: quad-per-row coalesced loads (64B/quad), 1024 threads ============
__global__ __launch_bounds__(1024, 2) void phase_kernel(const float* __restrict__ lin_z,
                                                        const float* __restrict__ bo,
                                                        const float* __restrict__ Gr,
                                                        const float* __restrict__ Gi,
                                                        const float* __restrict__ hrr,
                                                        const float* __restrict__ hri,
                                                        float* __restrict__ accum)
{
  const int b = blockIdx.x;
  const int tid = threadIdx.x;
  __shared__ float psum[4][200];
  __shared__ float lsh[200];
  __shared__ float u[100];
  __shared__ float pq[100];
  __shared__ float wred[16];

  if (tid < 800){
    int zq = tid / 200, j = tid - zq*200;
    int z0 = (zq == 0) ? 0 : (6*zq + 1);
    int zn = (zq == 0) ? 7 : 6;
    float a = 0.f;
    for (int z = z0; z < z0 + zn; ++z)
      a += lin_z[((size_t)z*512 + b)*208 + j];
    psum[zq][j] = a;
  }
  __syncthreads();
  if (tid < 200)
    lsh[tid] = bo[tid] + psum[0][tid] + psum[1][tid] + psum[2][tid] + psum[3][tid];
  __syncthreads();
  if (tid < 100){
    float c = cosf(lsh[tid]);
    float s = sinf(lsh[100 + tid]);
    float hr = hrr[b*100 + tid];
    float hi = hri[b*100 + tid];
    u[tid]  = c*hr - s*hi;
    pq[tid] = c*hi + s*hr;
  }
  __syncthreads();

  const int m = tid >> 2, q = tid & 3;
  const float4* grow  = (const float4*)(Gr + ((size_t)b*256 + m)*100);
  const float4* girow = (const float4*)(Gi + ((size_t)b*256 + m)*100);
  float tr = 0.f, ti = 0.f;
#pragma unroll
  for (int k = 0; k < 6; ++k){
    int i = q + 4*k;
    float4 g  = grow[i];
    float4 gg = girow[i];
    float4 uu = *(const float4*)&u[i*4];
    float4 qq = *(const float4*)&pq[i*4];
    tr += g.x*uu.x - gg.x*qq.x;  ti += g.x*qq.x + gg.x*uu.x;
    tr += g.y*uu.y - gg.y*qq.y;  ti += g.y*qq.y + gg.y*uu.y;
    tr += g.z*uu.z - gg.z*qq.z;  ti += g.z*qq.z + gg.z*uu.z;
    tr += g.w*uu.w - gg.w*qq.w;  ti += g.w*qq.w + gg.w*uu.w;
  }
  if (q == 0){
    float4 g  = grow[24];
    float4 gg = girow[24];
    float4 uu = *(const float4*)&u[96];
    float4 qq = *(const float4*)&pq[96];
    tr += g.x*uu.x - gg.x*qq.x;  ti += g.x*qq.x + gg.x*uu.x;
    tr += g.y*uu.y - gg.y*qq.y;  ti += g.y*qq.y + gg.y*uu.y;
    tr += g.z*uu.z - gg.z*qq.z;  ti += g.z*qq.z + gg.z*uu.z;
    tr += g.w*uu.w - gg.w*qq.w;  ti += g.w*qq.w + gg.w*uu.w;
  }
  tr += __shfl_xor(tr, 1); tr += __shfl_xor(tr, 2);
  ti += __shfl_xor(ti, 1); ti += __shfl_xor(ti, 2);
  float ns = (q == 0) ? (tr*tr + ti*ti) : 0.f;
#pragma unroll
  for (int off = 4; off < 64; off <<= 1) ns += __shfl_down(ns, off);
  if ((tid & 63) == 0) wred[tid >> 6] = ns;
  __syncthreads();
  if (tid == 0){
    float t = 0.f;
#pragma unroll
    for (int w = 0; w < 16; ++w) t += wred[w];
    atomicAdd(accum, t);
  }
}

__global__ void finalize_kernel(const float* __restrict__ accum, float* __restrict__ out)
{
  out[0] = -accum[0] * (1.0f / 512.0f);
}

extern "C" void kernel_launch(void* const* d_in, const int* in_sizes, int n_in,
                              void* d_out, int out_size, void* d_ws, size_t ws_size,
                              hipStream_t stream)
{
  const float* F   = (const float*)d_in[0];
  const float* Gr  = (const float*)d_in[1];
  const float* Gi  = (const float*)d_in[2];
  const float* hrr = (const float*)d_in[3];
  const float* hri = (const float*)d_in[4];
  const float* W1  = (const float*)d_in[5];
  const float* b1  = (const float*)d_in[6];
  const float* g1  = (const float*)d_in[7];
  const float* be1 = (const float*)d_in[8];
  const float* W2  = (const float*)d_in[9];
  const float* b2  = (const float*)d_in[10];
  const float* g2  = (const float*)d_in[11];
  const float* be2 = (const float*)d_in[12];
  const float* W3  = (const float*)d_in[13];
  const float* b3  = (const float*)d_in[14];
  const float* g3  = (const float*)d_in[15];
  const float* be3 = (const float*)d_in[16];
  const float* W4  = (const float*)d_in[17];
  const float* b4  = (const float*)d_in[18];
  const float* g4  = (const float*)d_in[19];
  const float* be4 = (const float*)d_in[20];
  const float* Wo  = (const float*)d_in[21];
  const float* bo  = (const float*)d_in[22];

  char* ws = (char*)d_ws;
  unsigned short* y1   = (unsigned short*)(ws);
  unsigned short* y2   = (unsigned short*)(ws + 52428800);
  unsigned short* y3   = (unsigned short*)(ws);
  unsigned short* y4   = (unsigned short*)(ws + 52428800);
  unsigned short* Wob  = (unsigned short*)(ws + 65536000);   // 256x12800 bf16
  float*          lin_z= (float*)(ws + 13107200);            // 25x512x208 f32
  float* stats = (float*)(ws + 78643200);                    // 2304 f32
  float* ssb   = (float*)(ws + 78652416);                    // 1024 f32
  float* accum = (float*)(ws + 78656512);                    // 16 B
  unsigned short* Wpk1 = (unsigned short*)(ws + 78656528);
  unsigned short* Wpk2 = (unsigned short*)(ws + 78664720);
  unsigned short* Wpk3 = (unsigned short*)(ws + 78812176);
  unsigned short* Wpk4 = (unsigned short*)(ws + 78885904);

  hipMemsetAsync(ws + 78643200, 0, 13328, stream);

  const float invN = 1.0f / 204800.0f;

  packw1_kernel<<<2, 256, 0, stream>>>(W1, Wpk1);
  packw_kernel<<<36, 256, 0, stream>>>(W2, Wpk2, 4, 128, 9216);  // NCC=4, CT=4
  packw_kernel<<<18, 256, 0, stream>>>(W3, Wpk3, 4, 64, 4608);   // NCC=2, CT=4
  packw_kernel<<< 9, 256, 0, stream>>>(W4, Wpk4, 2, 64, 2304);   // NCC=2, CT=2

  conv1_mfma<<<512, 256, 0, stream>>>(F, Wpk1, b1, y1, stats);
  bn_fin<<<1, 128, 0, stream>>>(stats, g1, be1, ssb, 128, invN, 4);

  conv_mfma<128, 64><<<512, 512, 0, stream>>>(y1, ssb, Wpk2, b2, y2, stats + 1024);
  bn_fin<<<1, 64, 0, stream>>>(stats + 1024, g2, be2, ssb + 256, 64, invN, 4);

  conv_mfma<64, 64><<<512, 512, 0, stream>>>(y2, ssb + 256, Wpk3, b3, y3, stats + 1536);
  bn_fin<<<1, 64, 0, stream>>>(stats + 1536, g3, be3, ssb + 384, 64, invN, 4);

  conv_mfma<64, 32><<<512, 512, 0, stream>>>(y3, ssb + 384, Wpk4, b4, y4, stats + 2048);
  bn_fin<<<1, 32, 0, stream>>>(stats + 2048, g4, be4, ssb + 512, 32, invN, 4);

  wopack_kernel<<<256, 256, 0, stream>>>(Wo, Wob);

  linear_mfma<<<dim3(8, 4, 25), 256, 0, stream>>>(y4, ssb + 512, Wob, lin_z);

  phase_kernel<<<512, 1024, 0, stream>>>(lin_z, bo, Gr, Gi, hrr, hri, accum);
  finalize_kernel<<<1, 1, 0, stream>>>(accum, (float*)d_out);
}

// Round 22
// 182.681 us; speedup vs baseline: 1.0390x; 1.0390x over previous
//
#include <hip/hip_runtime.h>
#include <math.h>

typedef __bf16 bf16x8 __attribute__((ext_vector_type(8)));
typedef float f32x4 __attribute__((ext_vector_type(4)));
typedef unsigned short ushort8 __attribute__((ext_vector_type(8)));

__device__ __forceinline__ float bf2f(unsigned short u){ return __uint_as_float(((unsigned)u) << 16); }
__device__ __forceinline__ unsigned short f2bf(float f){
  unsigned v = __float_as_uint(f);
  return (unsigned short)((v + 0x7FFFu + ((v >> 16) & 1u)) >> 16);
}

// ---------- merged prep: wopack (blocks 0..255), packw1 (256..257), packw W2/W3/W4 ----------
__device__ __forceinline__ void packw_body(const float* __restrict__ W, unsigned short* __restrict__ Wpk,
                                           int CT, int CIN, int total, int idx)
{
  if (idx >= total) return;
  int lane = idx & 63;
  int t2 = idx >> 6;
  int dhw = t2 % 9;
  int t3 = t2 / 9;
  int ct = t3 % CT;
  int p  = t3 / CT;
  int co = ct*16 + (lane & 15);
  int ci0 = p*32 + (lane >> 4)*8;
#pragma unroll
  for (int j = 0; j < 8; ++j)
    Wpk[(size_t)idx*8 + j] = f2bf(W[((size_t)co*CIN + ci0 + j)*9 + dhw]);
}

__global__ __launch_bounds__(256) void prep_kernel(
    const float* __restrict__ W1, const float* __restrict__ W2,
    const float* __restrict__ W3, const float* __restrict__ W4,
    const float* __restrict__ Wo,
    unsigned short* __restrict__ Wpk1, unsigned short* __restrict__ Wpk2,
    unsigned short* __restrict__ Wpk3, unsigned short* __restrict__ Wpk4,
    unsigned short* __restrict__ Wob)
{
  __shared__ float row[12800];
  const int blk = blockIdx.x, tid = threadIdx.x;
  if (blk < 256){
    // wopack: Wo[j][c*400+p] -> Wob[j][p*32+c] bf16, rows 200..255 zero
    const int j = blk;
    if (j < 200){
      const float4* src = (const float4*)(Wo + (size_t)j*12800);
      for (int i = tid; i < 3200; i += 256) ((float4*)row)[i] = src[i];
      __syncthreads();
      for (int ko = tid; ko < 1600; ko += 256){
        int p = ko >> 2, c0 = (ko & 3)*8;
        union { unsigned short u[8]; uint4 v; } pk;
#pragma unroll
        for (int t = 0; t < 8; ++t) pk.u[t] = f2bf(row[(c0+t)*400 + p]);
        *(uint4*)(Wob + (size_t)j*12800 + ko*8) = pk.v;
      }
    } else {
      uint4 z = {0,0,0,0};
      for (int ko = tid; ko < 1600; ko += 256)
        *(uint4*)(Wob + (size_t)j*12800 + ko*8) = z;
    }
  } else if (blk < 258){
    // packw1: W1 [128][2][3][3] -> [ct=8][lane=64][8], k = ci*9+dhw, pad k>=18
    int idx = (blk - 256)*256 + tid;
    if (idx < 512){
      int lane = idx & 63, ct = idx >> 6;
      int co = ct*16 + (lane & 15);
      int lq = lane >> 4;
#pragma unroll
      for (int j = 0; j < 8; ++j){
        int k = lq*8 + j;
        Wpk1[(size_t)idx*8 + j] = (k < 18) ? f2bf(W1[(size_t)co*18 + k]) : (unsigned short)0;
      }
    }
  } else if (blk < 294){
    packw_body(W2, Wpk2, 4, 128, 9216, (blk - 258)*256 + tid);
  } else if (blk < 312){
    packw_body(W3, Wpk3, 4, 64, 4608, (blk - 294)*256 + tid);
  } else {
    packw_body(W4, Wpk4, 2, 64, 2304, (blk - 312)*256 + tid);
  }
}

// ================= conv1: 2->128 via single-K MFMA, fused stats =================
__global__ __launch_bounds__(256, 2) void conv1_mfma(
    const float* __restrict__ F, const unsigned short* __restrict__ Wpk1,
    const float* __restrict__ b1, unsigned short* __restrict__ y1,
    float* __restrict__ stats)
{
  __shared__ float xp[2*484];
  __shared__ float sred[256];
  const int tid = threadIdx.x, b = blockIdx.x;
  const int wid = tid >> 6, lane = tid & 63, lq = lane >> 4, lr = lane & 15;

  for (int i = tid; i < 256; i += 256) sred[i] = 0.f;
  for (int i = tid; i < 968; i += 256) xp[i] = 0.f;
  __syncthreads();
  for (int i = tid; i < 800; i += 256){
    int ci = i / 400, p = i - ci*400;
    xp[ci*484 + (p/20 + 1)*22 + (p%20) + 1] = F[((size_t)b*2 + ci)*400 + p];
  }
  __syncthreads();

  bf16x8 af[8];
#pragma unroll
  for (int ct = 0; ct < 8; ++ct)
    af[ct] = *(const bf16x8*)(Wpk1 + (size_t)(ct*64 + lane)*8);

  int off[8]; bool kval[8];
#pragma unroll
  for (int j = 0; j < 8; ++j){
    int k = lq*8 + j;
    kval[j] = (k < 18);
    int kc = kval[j] ? k : 0;
    int ci = kc / 9, dhw = kc - ci*9;
    off[j] = ci*484 + (dhw/3)*22 + (dhw - (dhw/3)*3);
  }

  f32x4 bias[8];
#pragma unroll
  for (int ct = 0; ct < 8; ++ct)
    bias[ct] = *(const f32x4*)(b1 + ct*16 + lq*4);

  float smv[8][4], sqv[8][4];
#pragma unroll
  for (int ct = 0; ct < 8; ++ct)
#pragma unroll
    for (int r = 0; r < 4; ++r){ smv[ct][r] = 0.f; sqv[ct][r] = 0.f; }

  for (int pt = wid; pt < 25; pt += 4){
    const int px = pt*16 + lr;
    const int h = px/20, w = px - (px/20)*20;
    const int base = h*22 + w;
    union { unsigned short u[8]; bf16x8 h8; } bfr;
#pragma unroll
    for (int j = 0; j < 8; ++j){
      float xv = kval[j] ? xp[base + off[j]] : 0.f;
      bfr.u[j] = f2bf(xv);
    }
    f32x4 zero4 = {0.f,0.f,0.f,0.f};
#pragma unroll
    for (int ct = 0; ct < 8; ++ct){
      f32x4 acc = __builtin_amdgcn_mfma_f32_16x16x32_bf16(af[ct], bfr.h8, zero4, 0, 0, 0);
      f32x4 y = acc + bias[ct];
      union { unsigned short u[4]; unsigned long long ll; } pk;
#pragma unroll
      for (int r = 0; r < 4; ++r){
        pk.u[r] = f2bf(y[r]);
        smv[ct][r] += y[r];
        sqv[ct][r] = fmaf(y[r], y[r], sqv[ct][r]);
      }
      *(unsigned long long*)(y1 + ((size_t)b*400 + px)*128 + ct*16 + lq*4) = pk.ll;
    }
  }

#pragma unroll
  for (int ct = 0; ct < 8; ++ct)
#pragma unroll
    for (int r = 0; r < 4; ++r){
      float v = smv[ct][r], q = sqv[ct][r];
#pragma unroll
      for (int m = 1; m < 16; m <<= 1){ v += __shfl_xor(v, m); q += __shfl_xor(q, m); }
      if (lr == 0){
        int co = ct*16 + lq*4 + r;
        atomicAdd(&sred[co], v);
        atomicAdd(&sred[128 + co], q);
      }
    }
  __syncthreads();
  float* st = stats + (size_t)(b & 3) * 256;
  for (int i = tid; i < 256; i += 256)
    atomicAdd(&st[i], sred[i]);
}

// ===== MFMA implicit-GEMM conv 3x3 SAME (v14: fused input-BN-finalize, coalesced C-write) =====
// stats_in: 4 slices of [2*CIN] (sum, sumsq); g/be: input-layer BN params.
template<int CIN, int COUT>
__global__ __launch_bounds__(512, 4) void conv_mfma(
    const unsigned short* __restrict__ xin, const float* __restrict__ stats_in,
    const float* __restrict__ g, const float* __restrict__ be,
    const unsigned short* __restrict__ Wpk, const float* __restrict__ bconv,
    unsigned short* __restrict__ yout, float* __restrict__ stats_out)
{
  constexpr int NCC = CIN/32;
  constexpr int CT  = COUT/16;
  constexpr int WCH = CT*9*64;
  __shared__ unsigned short xs[484*5*8];
  __shared__ unsigned short wl[WCH*8];
  __shared__ float sred[2*COUT];
  __shared__ __align__(16) float ssl[2*CIN];

  const int tid = threadIdx.x, b = blockIdx.x;
  const int wid = tid >> 6, lane = tid & 63, lq = lane >> 4, lr = lane & 15;
  const int oct = tid & 3;

  for (int i = tid; i < 2*COUT; i += 512) sred[i] = 0.f;

  // ---- fused bn_fin: fold 4-sliced stats -> scale/shift in LDS ----
  for (int c = tid; c < CIN; c += 512){
    float s = 0.f, q = 0.f;
#pragma unroll
    for (int t = 0; t < 4; ++t){
      s += stats_in[t*2*CIN + c];
      q += stats_in[t*2*CIN + CIN + c];
    }
    float mean = s * 4.8828125e-6f;            // 1/204800
    float var  = q * 4.8828125e-6f - mean*mean;
    float sc   = g[c] * rsqrtf(var + 1e-5f);
    ssl[c]       = sc;
    ssl[CIN + c] = be[c] - mean*sc;
  }

  int pp[4];
#pragma unroll
  for (int s = 0; s < 4; ++s){
    int tile = (s < 3) ? (wid + 8*s) : 24;
    int px = tile*16 + lr;
    int prow = px/20, pcol = px - prow*20;
    pp[s] = (prow + 1)*22 + (pcol + 1);
  }

  f32x4 acc[CT][4];
#pragma unroll
  for (int ct = 0; ct < CT; ++ct)
#pragma unroll
    for (int s = 0; s < 4; ++s){ acc[ct][s][0]=0.f; acc[ct][s][1]=0.f; acc[ct][s][2]=0.f; acc[ct][s][3]=0.f; }

  for (int p = 0; p < NCC; ++p){
    __syncthreads();   // pass 0: also covers ssl/sred init
    for (int i = tid; i < WCH; i += 512)
      *(uint4*)&wl[(size_t)i*8] = *(const uint4*)(Wpk + ((size_t)p*WCH + i)*8);
    {
      const int c = p*32 + oct*8;
      f32x4 s0 = *(const f32x4*)(ssl + c);
      f32x4 s1 = *(const f32x4*)(ssl + c + 4);
      f32x4 h0 = *(const f32x4*)(ssl + CIN + c);
      f32x4 h1 = *(const f32x4*)(ssl + CIN + c + 4);
      for (int i = tid; i < 484*4; i += 512){
        int pidx = i >> 2;
        int r22 = pidx/22, c22 = pidx - r22*22;
        int row = r22 - 1, col = c22 - 1;
        union { unsigned short u[8]; uint4 v; } pk;
        if ((unsigned)row < 20u && (unsigned)col < 20u){
          ushort8 raw = *(const ushort8*)(xin + ((size_t)b*400 + row*20 + col)*CIN + c);
          pk.u[0] = f2bf(fmaxf(fmaf(bf2f(raw[0]), s0[0], h0[0]), 0.f));
          pk.u[1] = f2bf(fmaxf(fmaf(bf2f(raw[1]), s0[1], h0[1]), 0.f));
          pk.u[2] = f2bf(fmaxf(fmaf(bf2f(raw[2]), s0[2], h0[2]), 0.f));
          pk.u[3] = f2bf(fmaxf(fmaf(bf2f(raw[3]), s0[3], h0[3]), 0.f));
          pk.u[4] = f2bf(fmaxf(fmaf(bf2f(raw[4]), s1[0], h1[0]), 0.f));
          pk.u[5] = f2bf(fmaxf(fmaf(bf2f(raw[5]), s1[1], h1[1]), 0.f));
          pk.u[6] = f2bf(fmaxf(fmaf(bf2f(raw[6]), s1[2], h1[2]), 0.f));
          pk.u[7] = f2bf(fmaxf(fmaf(bf2f(raw[7]), s1[3], h1[3]), 0.f));
        } else {
          pk.v.x = 0u; pk.v.y = 0u; pk.v.z = 0u; pk.v.w = 0u;
        }
        *(uint4*)&xs[(size_t)(pidx*5 + oct)*8] = pk.v;
      }
    }
    __syncthreads();

#pragma unroll
    for (int dhw = 0; dhw < 9; ++dhw){
      const int doff = (dhw/3 - 1)*22 + (dhw - (dhw/3)*3 - 1);
      bf16x8 af[CT];
#pragma unroll
      for (int ct = 0; ct < CT; ++ct)
        af[ct] = *(const bf16x8*)&wl[(size_t)((ct*9 + dhw)*64 + lane)*8];
#pragma unroll
      for (int s = 0; s < 4; ++s){
        if (s == 3 && wid != 0) continue;   // wave-uniform: only wave 0 owns tile 24
        bf16x8 bf = *(const bf16x8*)&xs[(size_t)((pp[s] + doff)*5 + lq)*8];
#pragma unroll
        for (int ct = 0; ct < CT; ++ct)
          acc[ct][s] = __builtin_amdgcn_mfma_f32_16x16x32_bf16(af[ct], bf, acc[ct][s], 0, 0, 0);
      }
    }
  }

  // ---- stats (in-reg) ----
  f32x4 biasv[CT];
#pragma unroll
  for (int ct = 0; ct < CT; ++ct) biasv[ct] = *(const f32x4*)(bconv + ct*16 + lq*4);

  float smv[CT][4], sqv[CT][4];
#pragma unroll
  for (int ct = 0; ct < CT; ++ct)
#pragma unroll
    for (int r = 0; r < 4; ++r){ smv[ct][r] = 0.f; sqv[ct][r] = 0.f; }

#pragma unroll
  for (int ct = 0; ct < CT; ++ct){
#pragma unroll
    for (int s = 0; s < 4; ++s){
      const bool valid = (s < 3) || (wid == 0);
      f32x4 y = acc[ct][s] + biasv[ct];
#pragma unroll
      for (int r = 0; r < 4; ++r){
        float yv = valid ? y[r] : 0.f;
        smv[ct][r] += yv;
        sqv[ct][r] = fmaf(yv, yv, sqv[ct][r]);
      }
    }
  }
#pragma unroll
  for (int ct = 0; ct < CT; ++ct)
#pragma unroll
    for (int r = 0; r < 4; ++r){
      float v = smv[ct][r], w2 = sqv[ct][r];
#pragma unroll
      for (int m = 1; m < 16; m <<= 1){ v += __shfl_xor(v, m); w2 += __shfl_xor(w2, m); }
      if (lr == 0){
        int co = ct*16 + lq*4 + r;
        atomicAdd(&sred[co], v);
        atomicAdd(&sred[COUT + co], w2);
      }
    }
  __syncthreads();
  {
    float* st = stats_out + (size_t)(b & 3) * 2 * COUT;
    for (int i = tid; i < 2*COUT; i += 512)
      atomicAdd(&st[i], sred[i]);
  }

  // ---- coalesced C-write: two px-phases through xs (reuse), 8B-slot XOR swizzle ----
  constexpr int SM  = COUT/4 - 1;
  constexpr int CPX = COUT/8;

  auto WSTORE = [&](int s, int base){
    int tile = (s < 3) ? (wid + 8*s) : 24;
    int pxl = tile*16 + lr - base;
#pragma unroll
    for (int ct = 0; ct < CT; ++ct){
      f32x4 y = acc[ct][s] + biasv[ct];
      union { unsigned short u[4]; unsigned long long ll; } pk;
#pragma unroll
      for (int r = 0; r < 4; ++r) pk.u[r] = f2bf(y[r]);
      int slot = (ct*4 + lq) ^ (pxl & SM);
      *(unsigned long long*)&xs[(size_t)pxl*COUT + slot*4] = pk.ll;
    }
  };
  auto CSTORE = [&](int base, int pxn){
    const int cnt = pxn * CPX;
    unsigned short* dst = yout + ((size_t)b*400 + base)*COUT;
    for (int i = tid; i < cnt; i += 512){
      int pxl = i / CPX, j = i - pxl*CPX;
      int m = pxl & SM;
      unsigned long long lo = *(unsigned long long*)&xs[(size_t)pxl*COUT + ((2*j)     ^ m)*4];
      unsigned long long hi = *(unsigned long long*)&xs[(size_t)pxl*COUT + ((2*j + 1) ^ m)*4];
      union { unsigned long long q[2]; uint4 v; } o; o.q[0] = lo; o.q[1] = hi;
      *(uint4*)&dst[(size_t)i*8] = o.v;
    }
  };

  WSTORE(0, 0);
  if (wid < 4) WSTORE(1, 0);
  __syncthreads();
  CSTORE(0, 192);
  __syncthreads();
  if (wid >= 4) WSTORE(1, 192);
  WSTORE(2, 192);
  if (wid == 0) WSTORE(3, 192);
  __syncthreads();
  CSTORE(192, 208);
}

// ====== linear: MFMA split-K, fused bn_fin(layer4) + BN+ReLU(y4) in A-stage ======
__global__ __launch_bounds__(256, 4) void linear_mfma(
    const unsigned short* __restrict__ y4, const float* __restrict__ stats_in,
    const float* __restrict__ g, const float* __restrict__ be,
    const unsigned short* __restrict__ Wob, float* __restrict__ lin_z)
{
  __shared__ unsigned short As[64*128];
  __shared__ unsigned short Bs[64*128];
  __shared__ __align__(16) float ssl[64];
  const int tid = threadIdx.x;
  const int m0 = blockIdx.x * 64;
  const int j0 = blockIdx.y * 64;
  const int z  = blockIdx.z;
  const int wid = tid >> 6, lane = tid & 63, lq = lane >> 4, lr = lane & 15;
  const int srow = tid >> 4, soct = tid & 15;
  const int c0 = (soct & 3) * 8;

  // fused bn_fin for layer 4 (C=32, 4 slices of [64])
  if (tid < 32){
    int c = tid;
    float s = 0.f, q = 0.f;
#pragma unroll
    for (int t = 0; t < 4; ++t){ s += stats_in[t*64 + c]; q += stats_in[t*64 + 32 + c]; }
    float mean = s * 4.8828125e-6f;
    float var  = q * 4.8828125e-6f - mean*mean;
    float sc   = g[c] * rsqrtf(var + 1e-5f);
    ssl[c]      = sc;
    ssl[32 + c] = be[c] - mean*sc;
  }
  __syncthreads();

  f32x4 s0 = *(const f32x4*)(ssl + c0);
  f32x4 s1 = *(const f32x4*)(ssl + c0 + 4);
  f32x4 h0 = *(const f32x4*)(ssl + 32 + c0);
  f32x4 h1 = *(const f32x4*)(ssl + 32 + c0 + 4);

  f32x4 acc[4];
#pragma unroll
  for (int ct = 0; ct < 4; ++ct){ acc[ct][0]=0.f; acc[ct][1]=0.f; acc[ct][2]=0.f; acc[ct][3]=0.f; }

  for (int ch = 0; ch < 4; ++ch){
    const int k0 = z*512 + ch*128;
    __syncthreads();
#pragma unroll
    for (int pass = 0; pass < 4; ++pass){
      int row = pass*16 + srow;
      ushort8 raw = *(const ushort8*)(y4 + (size_t)(m0+row)*12800 + k0 + soct*8);
      union { unsigned short u[8]; uint4 v; } pk;
      pk.u[0] = f2bf(fmaxf(fmaf(bf2f(raw[0]), s0[0], h0[0]), 0.f));
      pk.u[1] = f2bf(fmaxf(fmaf(bf2f(raw[1]), s0[1], h0[1]), 0.f));
      pk.u[2] = f2bf(fmaxf(fmaf(bf2f(raw[2]), s0[2], h0[2]), 0.f));
      pk.u[3] = f2bf(fmaxf(fmaf(bf2f(raw[3]), s0[3], h0[3]), 0.f));
      pk.u[4] = f2bf(fmaxf(fmaf(bf2f(raw[4]), s1[0], h1[0]), 0.f));
      pk.u[5] = f2bf(fmaxf(fmaf(bf2f(raw[5]), s1[1], h1[1]), 0.f));
      pk.u[6] = f2bf(fmaxf(fmaf(bf2f(raw[6]), s1[2], h1[2]), 0.f));
      pk.u[7] = f2bf(fmaxf(fmaf(bf2f(raw[7]), s1[3], h1[3]), 0.f));
      *(uint4*)&As[(size_t)((row << 4) + (soct ^ (row & 7)))*8] = pk.v;
      uint4 wv = *(const uint4*)(Wob + (size_t)(j0+row)*12800 + k0 + soct*8);
      *(uint4*)&Bs[(size_t)((row << 4) + (soct ^ (row & 7)))*8] = wv;
    }
    __syncthreads();
#pragma unroll
    for (int ks = 0; ks < 4; ++ks){
      const int arow = wid*16 + lr;
      bf16x8 afr = *(const bf16x8*)&As[(size_t)((arow << 4) + ((ks*4 + lq) ^ (arow & 7)))*8];
#pragma unroll
      for (int ct = 0; ct < 4; ++ct){
        const int brow = ct*16 + lr;
        bf16x8 bfr = *(const bf16x8*)&Bs[(size_t)((brow << 4) + ((ks*4 + lq) ^ (brow & 7)))*8];
        acc[ct] = __builtin_amdgcn_mfma_f32_16x16x32_bf16(afr, bfr, acc[ct], 0, 0, 0);
      }
    }
  }
#pragma unroll
  for (int ct = 0; ct < 4; ++ct){
    int j = j0 + ct*16 + lr;
    if (j < 208){
#pragma unroll
      for (int r = 0; r < 4; ++r){
        int m = m0 + wid*16 + lq*4 + r;
        lin_z[((size_t)z*512 + m)*208 + j] = acc[ct][r];
      }
    }
  }
}

// ============ phase: quad-per-row coalesced loads (64B/quad), 1024 threads ============
__global__ __launch_bounds__(1024, 2) void phase_kernel(const float* __restrict__ lin_z,
                                                        const float* __restrict__ bo,
                                                        const float* __restrict__ Gr,
                                                        const float* __restrict__ Gi,
                                                        const float* __restrict__ hrr,
                                                        const float* __restrict__ hri,
                                                        float* __restrict__ accum)
{
  const int b = blockIdx.x;
  const int tid = threadIdx.x;
  __shared__ float psum[4][200];
  __shared__ float lsh[200];
  __shared__ float u[100];
  __shared__ float pq[100];
  __shared__ float wred[16];

  if (tid < 800){
    int zq = tid / 200, j = tid - zq*200;
    int z0 = (zq == 0) ? 0 : (6*zq + 1);
    int zn = (zq == 0) ? 7 : 6;
    float a = 0.f;
    for (int z = z0; z < z0 + zn; ++z)
      a += lin_z[((size_t)z*512 + b)*208 + j];
    psum[zq][j] = a;
  }
  __syncthreads();
  if (tid < 200)
    lsh[tid] = bo[tid] + psum[0][tid] + psum[1][tid] + psum[2][tid] + psum[3][tid];
  __syncthreads();
  if (tid < 100){
    float c = cosf(lsh[tid]);
    float s = sinf(lsh[100 + tid]);
    float hr = hrr[b*100 + tid];
    float hi = hri[b*100 + tid];
    u[tid]  = c*hr - s*hi;
    pq[tid] = c*hi + s*hr;
  }
  __syncthreads();

  const int m = tid >> 2, q = tid & 3;
  const float4* grow  = (const float4*)(Gr + ((size_t)b*256 + m)*100);
  const float4* girow = (const float4*)(Gi + ((size_t)b*256 + m)*100);
  float tr = 0.f, ti = 0.f;
#pragma unroll
  for (int k = 0; k < 6; ++k){
    int i = q + 4*k;
    float4 g  = grow[i];
    float4 gg = girow[i];
    float4 uu = *(const float4*)&u[i*4];
    float4 qq = *(const float4*)&pq[i*4];
    tr += g.x*uu.x - gg.x*qq.x;  ti += g.x*qq.x + gg.x*uu.x;
    tr += g.y*uu.y - gg.y*qq.y;  ti += g.y*qq.y + gg.y*uu.y;
    tr += g.z*uu.z - gg.z*qq.z;  ti += g.z*qq.z + gg.z*uu.z;
    tr += g.w*uu.w - gg.w*qq.w;  ti += g.w*qq.w + gg.w*uu.w;
  }
  if (q == 0){
    float4 g  = grow[24];
    float4 gg = girow[24];
    float4 uu = *(const float4*)&u[96];
    float4 qq = *(const float4*)&pq[96];
    tr += g.x*uu.x - gg.x*qq.x;  ti += g.x*qq.x + gg.x*uu.x;
    tr += g.y*uu.y - gg.y*qq.y;  ti += g.y*qq.y + gg.y*uu.y;
    tr += g.z*uu.z - gg.z*qq.z;  ti += g.z*qq.z + gg.z*uu.z;
    tr += g.w*uu.w - gg.w*qq.w;  ti += g.w*qq.w + gg.w*uu.w;
  }
  tr += __shfl_xor(tr, 1); tr += __shfl_xor(tr, 2);
  ti += __shfl_xor(ti, 1); ti += __shfl_xor(ti, 2);
  float ns = (q == 0) ? (tr*tr + ti*ti) : 0.f;
#pragma unroll
  for (int off = 4; off < 64; off <<= 1) ns += __shfl_down(ns, off);
  if ((tid & 63) == 0) wred[tid >> 6] = ns;
  __syncthreads();
  if (tid == 0){
    float t = 0.f;
#pragma unroll
    for (int w = 0; w < 16; ++w) t += wred[w];
    atomicAdd(accum, t);
  }
}

__global__ void finalize_kernel(const float* __restrict__ accum, float* __restrict__ out)
{
  out[0] = -accum[0] * (1.0f / 512.0f);
}

extern "C" void kernel_launch(void* const* d_in, const int* in_sizes, int n_in,
                              void* d_out, int out_size, void* d_ws, size_t ws_size,
                              hipStream_t stream)
{
  const float* F   = (const float*)d_in[0];
  const float* Gr  = (const float*)d_in[1];
  const float* Gi  = (const float*)d_in[2];
  const float* hrr = (const float*)d_in[3];
  const float* hri = (const float*)d_in[4];
  const float* W1  = (const float*)d_in[5];
  const float* b1  = (const float*)d_in[6];
  const float* g1  = (const float*)d_in[7];
  const float* be1 = (const float*)d_in[8];
  const float* W2  = (const float*)d_in[9];
  const float* b2  = (const float*)d_in[10];
  const float* g2  = (const float*)d_in[11];
  const float* be2 = (const float*)d_in[12];
  const float* W3  = (const float*)d_in[13];
  const float* b3  = (const float*)d_in[14];
  const float* g3  = (const float*)d_in[15];
  const float* be3 = (const float*)d_in[16];
  const float* W4  = (const float*)d_in[17];
  const float* b4  = (const float*)d_in[18];
  const float* g4  = (const float*)d_in[19];
  const float* be4 = (const float*)d_in[20];
  const float* Wo  = (const float*)d_in[21];
  const float* bo  = (const float*)d_in[22];

  char* ws = (char*)d_ws;
  unsigned short* y1   = (unsigned short*)(ws);
  unsigned short* y2   = (unsigned short*)(ws + 52428800);
  unsigned short* y3   = (unsigned short*)(ws);
  unsigned short* y4   = (unsigned short*)(ws + 52428800);
  unsigned short* Wob  = (unsigned short*)(ws + 65536000);   // 256x12800 bf16
  float*          lin_z= (float*)(ws + 13107200);            // 25x512x208 f32
  float* stats = (float*)(ws + 78643200);                    // 2304 f32
  float* accum = (float*)(ws + 78656512);                    // 16 B
  unsigned short* Wpk1 = (unsigned short*)(ws + 78656528);
  unsigned short* Wpk2 = (unsigned short*)(ws + 78664720);
  unsigned short* Wpk3 = (unsigned short*)(ws + 78812176);
  unsigned short* Wpk4 = (unsigned short*)(ws + 78885904);

  hipMemsetAsync(ws + 78643200, 0, 13328, stream);   // stats (+dead ssb region) + accum

  // one merged prep launch: wopack + all weight packs
  prep_kernel<<<321, 256, 0, stream>>>(W1, W2, W3, W4, Wo, Wpk1, Wpk2, Wpk3, Wpk4, Wob);

  conv1_mfma<<<512, 256, 0, stream>>>(F, Wpk1, b1, y1, stats);

  conv_mfma<128, 64><<<512, 512, 0, stream>>>(y1, stats,        g1, be1, Wpk2, b2, y2, stats + 1024);
  conv_mfma<64, 64><<<512, 512, 0, stream>>>( y2, stats + 1024, g2, be2, Wpk3, b3, y3, stats + 1536);
  conv_mfma<64, 32><<<512, 512, 0, stream>>>( y3, stats + 1536, g3, be3, Wpk4, b4, y4, stats + 2048);

  linear_mfma<<<dim3(8, 4, 25), 256, 0, stream>>>(y4, stats + 2048, g4, be4, Wob, lin_z);

  phase_kernel<<<512, 1024, 0, stream>>>(lin_z, bo, Gr, Gi, hrr, hri, accum);
  finalize_kernel<<<1, 1, 0, stream>>>(accum, (float*)d_out);
}

// Round 23
// 182.028 us; speedup vs baseline: 1.0427x; 1.0036x over previous
//
#include <hip/hip_runtime.h>
#include <math.h>

typedef __bf16 bf16x8 __attribute__((ext_vector_type(8)));
typedef float f32x4 __attribute__((ext_vector_type(4)));
typedef unsigned short ushort8 __attribute__((ext_vector_type(8)));

__device__ __forceinline__ float bf2f(unsigned short u){ return __uint_as_float(((unsigned)u) << 16); }
__device__ __forceinline__ unsigned short f2bf(float f){
  unsigned v = __float_as_uint(f);
  return (unsigned short)((v + 0x7FFFu + ((v >> 16) & 1u)) >> 16);
}

// ---------- merged weight prep: packw1 (blocks 0..1), packw W2/W3/W4 ----------
__device__ __forceinline__ void packw_body(const float* __restrict__ W, unsigned short* __restrict__ Wpk,
                                           int CT, int CIN, int total, int idx)
{
  if (idx >= total) return;
  int lane = idx & 63;
  int t2 = idx >> 6;
  int dhw = t2 % 9;
  int t3 = t2 / 9;
  int ct = t3 % CT;
  int p  = t3 / CT;
  int co = ct*16 + (lane & 15);
  int ci0 = p*32 + (lane >> 4)*8;
#pragma unroll
  for (int j = 0; j < 8; ++j)
    Wpk[(size_t)idx*8 + j] = f2bf(W[((size_t)co*CIN + ci0 + j)*9 + dhw]);
}

__global__ __launch_bounds__(256) void prep_kernel(
    const float* __restrict__ W1, const float* __restrict__ W2,
    const float* __restrict__ W3, const float* __restrict__ W4,
    unsigned short* __restrict__ Wpk1, unsigned short* __restrict__ Wpk2,
    unsigned short* __restrict__ Wpk3, unsigned short* __restrict__ Wpk4)
{
  const int blk = blockIdx.x, tid = threadIdx.x;
  if (blk < 2){
    // packw1: W1 [128][2][3][3] -> [ct=8][lane=64][8], k = ci*9+dhw, pad k>=18
    int idx = blk*256 + tid;
    if (idx < 512){
      int lane = idx & 63, ct = idx >> 6;
      int co = ct*16 + (lane & 15);
      int lq = lane >> 4;
#pragma unroll
      for (int j = 0; j < 8; ++j){
        int k = lq*8 + j;
        Wpk1[(size_t)idx*8 + j] = (k < 18) ? f2bf(W1[(size_t)co*18 + k]) : (unsigned short)0;
      }
    }
  } else if (blk < 38){
    packw_body(W2, Wpk2, 4, 128, 9216, (blk - 2)*256 + tid);
  } else if (blk < 56){
    packw_body(W3, Wpk3, 4, 64, 4608, (blk - 38)*256 + tid);
  } else {
    packw_body(W4, Wpk4, 2, 64, 2304, (blk - 56)*256 + tid);
  }
}

// ---------- wopack: Wo[j][c*400+p] -> Wob[j][p*32+c] bf16, rows 200..255 zero ----------
// MUST run after conv3 (Wob aliases the y2 region; y2 is dead only after conv3).
__global__ __launch_bounds__(256) void wopack_kernel(const float* __restrict__ Wo,
                                                     unsigned short* __restrict__ Wob)
{
  __shared__ float row[12800];
  const int j = blockIdx.x, tid = threadIdx.x;
  if (j < 200){
    const float4* src = (const float4*)(Wo + (size_t)j*12800);
    for (int i = tid; i < 3200; i += 256) ((float4*)row)[i] = src[i];
    __syncthreads();
    for (int ko = tid; ko < 1600; ko += 256){
      int p = ko >> 2, c0 = (ko & 3)*8;
      union { unsigned short u[8]; uint4 v; } pk;
#pragma unroll
      for (int t = 0; t < 8; ++t) pk.u[t] = f2bf(row[(c0+t)*400 + p]);
      *(uint4*)(Wob + (size_t)j*12800 + ko*8) = pk.v;
    }
  } else {
    uint4 z = {0,0,0,0};
    for (int ko = tid; ko < 1600; ko += 256)
      *(uint4*)(Wob + (size_t)j*12800 + ko*8) = z;
  }
}

// ================= conv1: 2->128 via single-K MFMA, fused stats =================
__global__ __launch_bounds__(256, 2) void conv1_mfma(
    const float* __restrict__ F, const unsigned short* __restrict__ Wpk1,
    const float* __restrict__ b1, unsigned short* __restrict__ y1,
    float* __restrict__ stats)
{
  __shared__ float xp[2*484];
  __shared__ float sred[256];
  const int tid = threadIdx.x, b = blockIdx.x;
  const int wid = tid >> 6, lane = tid & 63, lq = lane >> 4, lr = lane & 15;

  for (int i = tid; i < 256; i += 256) sred[i] = 0.f;
  for (int i = tid; i < 968; i += 256) xp[i] = 0.f;
  __syncthreads();
  for (int i = tid; i < 800; i += 256){
    int ci = i / 400, p = i - ci*400;
    xp[ci*484 + (p/20 + 1)*22 + (p%20) + 1] = F[((size_t)b*2 + ci)*400 + p];
  }
  __syncthreads();

  bf16x8 af[8];
#pragma unroll
  for (int ct = 0; ct < 8; ++ct)
    af[ct] = *(const bf16x8*)(Wpk1 + (size_t)(ct*64 + lane)*8);

  int off[8]; bool kval[8];
#pragma unroll
  for (int j = 0; j < 8; ++j){
    int k = lq*8 + j;
    kval[j] = (k < 18);
    int kc = kval[j] ? k : 0;
    int ci = kc / 9, dhw = kc - ci*9;
    off[j] = ci*484 + (dhw/3)*22 + (dhw - (dhw/3)*3);
  }

  f32x4 bias[8];
#pragma unroll
  for (int ct = 0; ct < 8; ++ct)
    bias[ct] = *(const f32x4*)(b1 + ct*16 + lq*4);

  float smv[8][4], sqv[8][4];
#pragma unroll
  for (int ct = 0; ct < 8; ++ct)
#pragma unroll
    for (int r = 0; r < 4; ++r){ smv[ct][r] = 0.f; sqv[ct][r] = 0.f; }

  for (int pt = wid; pt < 25; pt += 4){
    const int px = pt*16 + lr;
    const int h = px/20, w = px - (px/20)*20;
    const int base = h*22 + w;
    union { unsigned short u[8]; bf16x8 h8; } bfr;
#pragma unroll
    for (int j = 0; j < 8; ++j){
      float xv = kval[j] ? xp[base + off[j]] : 0.f;
      bfr.u[j] = f2bf(xv);
    }
    f32x4 zero4 = {0.f,0.f,0.f,0.f};
#pragma unroll
    for (int ct = 0; ct < 8; ++ct){
      f32x4 acc = __builtin_amdgcn_mfma_f32_16x16x32_bf16(af[ct], bfr.h8, zero4, 0, 0, 0);
      f32x4 y = acc + bias[ct];
      union { unsigned short u[4]; unsigned long long ll; } pk;
#pragma unroll
      for (int r = 0; r < 4; ++r){
        pk.u[r] = f2bf(y[r]);
        smv[ct][r] += y[r];
        sqv[ct][r] = fmaf(y[r], y[r], sqv[ct][r]);
      }
      *(unsigned long long*)(y1 + ((size_t)b*400 + px)*128 + ct*16 + lq*4) = pk.ll;
    }
  }

#pragma unroll
  for (int ct = 0; ct < 8; ++ct)
#pragma unroll
    for (int r = 0; r < 4; ++r){
      float v = smv[ct][r], q = sqv[ct][r];
#pragma unroll
      for (int m = 1; m < 16; m <<= 1){ v += __shfl_xor(v, m); q += __shfl_xor(q, m); }
      if (lr == 0){
        int co = ct*16 + lq*4 + r;
        atomicAdd(&sred[co], v);
        atomicAdd(&sred[128 + co], q);
      }
    }
  __syncthreads();
  float* st = stats + (size_t)(b & 3) * 256;
  for (int i = tid; i < 256; i += 256)
    atomicAdd(&st[i], sred[i]);
}

// ===== MFMA implicit-GEMM conv 3x3 SAME (v14: fused input-BN-finalize, coalesced C-write) =====
template<int CIN, int COUT>
__global__ __launch_bounds__(512, 4) void conv_mfma(
    const unsigned short* __restrict__ xin, const float* __restrict__ stats_in,
    const float* __restrict__ g, const float* __restrict__ be,
    const unsigned short* __restrict__ Wpk, const float* __restrict__ bconv,
    unsigned short* __restrict__ yout, float* __restrict__ stats_out)
{
  constexpr int NCC = CIN/32;
  constexpr int CT  = COUT/16;
  constexpr int WCH = CT*9*64;
  __shared__ unsigned short xs[484*5*8];
  __shared__ unsigned short wl[WCH*8];
  __shared__ float sred[2*COUT];
  __shared__ __align__(16) float ssl[2*CIN];

  const int tid = threadIdx.x, b = blockIdx.x;
  const int wid = tid >> 6, lane = tid & 63, lq = lane >> 4, lr = lane & 15;
  const int oct = tid & 3;

  for (int i = tid; i < 2*COUT; i += 512) sred[i] = 0.f;

  // ---- fused bn_fin: fold 4-sliced stats -> scale/shift in LDS ----
  for (int c = tid; c < CIN; c += 512){
    float s = 0.f, q = 0.f;
#pragma unroll
    for (int t = 0; t < 4; ++t){
      s += stats_in[t*2*CIN + c];
      q += stats_in[t*2*CIN + CIN + c];
    }
    float mean = s * 4.8828125e-6f;            // 1/204800
    float var  = q * 4.8828125e-6f - mean*mean;
    float sc   = g[c] * rsqrtf(var + 1e-5f);
    ssl[c]       = sc;
    ssl[CIN + c] = be[c] - mean*sc;
  }

  int pp[4];
#pragma unroll
  for (int s = 0; s < 4; ++s){
    int tile = (s < 3) ? (wid + 8*s) : 24;
    int px = tile*16 + lr;
    int prow = px/20, pcol = px - prow*20;
    pp[s] = (prow + 1)*22 + (pcol + 1);
  }

  f32x4 acc[CT][4];
#pragma unroll
  for (int ct = 0; ct < CT; ++ct)
#pragma unroll
    for (int s = 0; s < 4; ++s){ acc[ct][s][0]=0.f; acc[ct][s][1]=0.f; acc[ct][s][2]=0.f; acc[ct][s][3]=0.f; }

  for (int p = 0; p < NCC; ++p){
    __syncthreads();   // pass 0: also covers ssl/sred init
    for (int i = tid; i < WCH; i += 512)
      *(uint4*)&wl[(size_t)i*8] = *(const uint4*)(Wpk + ((size_t)p*WCH + i)*8);
    {
      const int c = p*32 + oct*8;
      f32x4 s0 = *(const f32x4*)(ssl + c);
      f32x4 s1 = *(const f32x4*)(ssl + c + 4);
      f32x4 h0 = *(const f32x4*)(ssl + CIN + c);
      f32x4 h1 = *(const f32x4*)(ssl + CIN + c + 4);
      for (int i = tid; i < 484*4; i += 512){
        int pidx = i >> 2;
        int r22 = pidx/22, c22 = pidx - r22*22;
        int row = r22 - 1, col = c22 - 1;
        union { unsigned short u[8]; uint4 v; } pk;
        if ((unsigned)row < 20u && (unsigned)col < 20u){
          ushort8 raw = *(const ushort8*)(xin + ((size_t)b*400 + row*20 + col)*CIN + c);
          pk.u[0] = f2bf(fmaxf(fmaf(bf2f(raw[0]), s0[0], h0[0]), 0.f));
          pk.u[1] = f2bf(fmaxf(fmaf(bf2f(raw[1]), s0[1], h0[1]), 0.f));
          pk.u[2] = f2bf(fmaxf(fmaf(bf2f(raw[2]), s0[2], h0[2]), 0.f));
          pk.u[3] = f2bf(fmaxf(fmaf(bf2f(raw[3]), s0[3], h0[3]), 0.f));
          pk.u[4] = f2bf(fmaxf(fmaf(bf2f(raw[4]), s1[0], h1[0]), 0.f));
          pk.u[5] = f2bf(fmaxf(fmaf(bf2f(raw[5]), s1[1], h1[1]), 0.f));
          pk.u[6] = f2bf(fmaxf(fmaf(bf2f(raw[6]), s1[2], h1[2]), 0.f));
          pk.u[7] = f2bf(fmaxf(fmaf(bf2f(raw[7]), s1[3], h1[3]), 0.f));
        } else {
          pk.v.x = 0u; pk.v.y = 0u; pk.v.z = 0u; pk.v.w = 0u;
        }
        *(uint4*)&xs[(size_t)(pidx*5 + oct)*8] = pk.v;
      }
    }
    __syncthreads();

#pragma unroll
    for (int dhw = 0; dhw < 9; ++dhw){
      const int doff = (dhw/3 - 1)*22 + (dhw - (dhw/3)*3 - 1);
      bf16x8 af[CT];
#pragma unroll
      for (int ct = 0; ct < CT; ++ct)
        af[ct] = *(const bf16x8*)&wl[(size_t)((ct*9 + dhw)*64 + lane)*8];
#pragma unroll
      for (int s = 0; s < 4; ++s){
        if (s == 3 && wid != 0) continue;   // wave-uniform: only wave 0 owns tile 24
        bf16x8 bf = *(const bf16x8*)&xs[(size_t)((pp[s] + doff)*5 + lq)*8];
#pragma unroll
        for (int ct = 0; ct < CT; ++ct)
          acc[ct][s] = __builtin_amdgcn_mfma_f32_16x16x32_bf16(af[ct], bf, acc[ct][s], 0, 0, 0);
      }
    }
  }

  // ---- stats (in-reg) ----
  f32x4 biasv[CT];
#pragma unroll
  for (int ct = 0; ct < CT; ++ct) biasv[ct] = *(const f32x4*)(bconv + ct*16 + lq*4);

  float smv[CT][4], sqv[CT][4];
#pragma unroll
  for (int ct = 0; ct < CT; ++ct)
#pragma unroll
    for (int r = 0; r < 4; ++r){ smv[ct][r] = 0.f; sqv[ct][r] = 0.f; }

#pragma unroll
  for (int ct = 0; ct < CT; ++ct){
#pragma unroll
    for (int s = 0; s < 4; ++s){
      const bool valid = (s < 3) || (wid == 0);
      f32x4 y = acc[ct][s] + biasv[ct];
#pragma unroll
      for (int r = 0; r < 4; ++r){
        float yv = valid ? y[r] : 0.f;
        smv[ct][r] += yv;
        sqv[ct][r] = fmaf(yv, yv, sqv[ct][r]);
      }
    }
  }
#pragma unroll
  for (int ct = 0; ct < CT; ++ct)
#pragma unroll
    for (int r = 0; r < 4; ++r){
      float v = smv[ct][r], w2 = sqv[ct][r];
#pragma unroll
      for (int m = 1; m < 16; m <<= 1){ v += __shfl_xor(v, m); w2 += __shfl_xor(w2, m); }
      if (lr == 0){
        int co = ct*16 + lq*4 + r;
        atomicAdd(&sred[co], v);
        atomicAdd(&sred[COUT + co], w2);
      }
    }
  __syncthreads();
  {
    float* st = stats_out + (size_t)(b & 3) * 2 * COUT;
    for (int i = tid; i < 2*COUT; i += 512)
      atomicAdd(&st[i], sred[i]);
  }

  // ---- coalesced C-write: two px-phases through xs (reuse), 8B-slot XOR swizzle ----
  constexpr int SM  = COUT/4 - 1;
  constexpr int CPX = COUT/8;

  auto WSTORE = [&](int s, int base){
    int tile = (s < 3) ? (wid + 8*s) : 24;
    int pxl = tile*16 + lr - base;
#pragma unroll
    for (int ct = 0; ct < CT; ++ct){
      f32x4 y = acc[ct][s] + biasv[ct];
      union { unsigned short u[4]; unsigned long long ll; } pk;
#pragma unroll
      for (int r = 0; r < 4; ++r) pk.u[r] = f2bf(y[r]);
      int slot = (ct*4 + lq) ^ (pxl & SM);
      *(unsigned long long*)&xs[(size_t)pxl*COUT + slot*4] = pk.ll;
    }
  };
  auto CSTORE = [&](int base, int pxn){
    const int cnt = pxn * CPX;
    unsigned short* dst = yout + ((size_t)b*400 + base)*COUT;
    for (int i = tid; i < cnt; i += 512){
      int pxl = i / CPX, j = i - pxl*CPX;
      int m = pxl & SM;
      unsigned long long lo = *(unsigned long long*)&xs[(size_t)pxl*COUT + ((2*j)     ^ m)*4];
      unsigned long long hi = *(unsigned long long*)&xs[(size_t)pxl*COUT + ((2*j + 1) ^ m)*4];
      union { unsigned long long q[2]; uint4 v; } o; o.q[0] = lo; o.q[1] = hi;
      *(uint4*)&dst[(size_t)i*8] = o.v;
    }
  };

  WSTORE(0, 0);
  if (wid < 4) WSTORE(1, 0);
  __syncthreads();
  CSTORE(0, 192);
  __syncthreads();
  if (wid >= 4) WSTORE(1, 192);
  WSTORE(2, 192);
  if (wid == 0) WSTORE(3, 192);
  __syncthreads();
  CSTORE(192, 208);
}

// ====== linear: MFMA split-K, fused bn_fin(layer4) + BN+ReLU(y4) in A-stage ======
__global__ __launch_bounds__(256, 4) void linear_mfma(
    const unsigned short* __restrict__ y4, const float* __restrict__ stats_in,
    const float* __restrict__ g, const float* __restrict__ be,
    const unsigned short* __restrict__ Wob, float* __restrict__ lin_z)
{
  __shared__ unsigned short As[64*128];
  __shared__ unsigned short Bs[64*128];
  __shared__ __align__(16) float ssl[64];
  const int tid = threadIdx.x;
  const int m0 = blockIdx.x * 64;
  const int j0 = blockIdx.y * 64;
  const int z  = blockIdx.z;
  const int wid = tid >> 6, lane = tid & 63, lq = lane >> 4, lr = lane & 15;
  const int srow = tid >> 4, soct = tid & 15;
  const int c0 = (soct & 3) * 8;

  if (tid < 32){
    int c = tid;
    float s = 0.f, q = 0.f;
#pragma unroll
    for (int t = 0; t < 4; ++t){ s += stats_in[t*64 + c]; q += stats_in[t*64 + 32 + c]; }
    float mean = s * 4.8828125e-6f;
    float var  = q * 4.8828125e-6f - mean*mean;
    float sc   = g[c] * rsqrtf(var + 1e-5f);
    ssl[c]      = sc;
    ssl[32 + c] = be[c] - mean*sc;
  }
  __syncthreads();

  f32x4 s0 = *(const f32x4*)(ssl + c0);
  f32x4 s1 = *(const f32x4*)(ssl + c0 + 4);
  f32x4 h0 = *(const f32x4*)(ssl + 32 + c0);
  f32x4 h1 = *(const f32x4*)(ssl + 32 + c0 + 4);

  f32x4 acc[4];
#pragma unroll
  for (int ct = 0; ct < 4; ++ct){ acc[ct][0]=0.f; acc[ct][1]=0.f; acc[ct][2]=0.f; acc[ct][3]=0.f; }

  for (int ch = 0; ch < 4; ++ch){
    const int k0 = z*512 + ch*128;
    __syncthreads();
#pragma unroll
    for (int pass = 0; pass < 4; ++pass){
      int row = pass*16 + srow;
      ushort8 raw = *(const ushort8*)(y4 + (size_t)(m0+row)*12800 + k0 + soct*8);
      union { unsigned short u[8]; uint4 v; } pk;
      pk.u[0] = f2bf(fmaxf(fmaf(bf2f(raw[0]), s0[0], h0[0]), 0.f));
      pk.u[1] = f2bf(fmaxf(fmaf(bf2f(raw[1]), s0[1], h0[1]), 0.f));
      pk.u[2] = f2bf(fmaxf(fmaf(bf2f(raw[2]), s0[2], h0[2]), 0.f));
      pk.u[3] = f2bf(fmaxf(fmaf(bf2f(raw[3]), s0[3], h0[3]), 0.f));
      pk.u[4] = f2bf(fmaxf(fmaf(bf2f(raw[4]), s1[0], h1[0]), 0.f));
      pk.u[5] = f2bf(fmaxf(fmaf(bf2f(raw[5]), s1[1], h1[1]), 0.f));
      pk.u[6] = f2bf(fmaxf(fmaf(bf2f(raw[6]), s1[2], h1[2]), 0.f));
      pk.u[7] = f2bf(fmaxf(fmaf(bf2f(raw[7]), s1[3], h1[3]), 0.f));
      *(uint4*)&As[(size_t)((row << 4) + (soct ^ (row & 7)))*8] = pk.v;
      uint4 wv = *(const uint4*)(Wob + (size_t)(j0+row)*12800 + k0 + soct*8);
      *(uint4*)&Bs[(size_t)((row << 4) + (soct ^ (row & 7)))*8] = wv;
    }
    __syncthreads();
#pragma unroll
    for (int ks = 0; ks < 4; ++ks){
      const int arow = wid*16 + lr;
      bf16x8 afr = *(const bf16x8*)&As[(size_t)((arow << 4) + ((ks*4 + lq) ^ (arow & 7)))*8];
#pragma unroll
      for (int ct = 0; ct < 4; ++ct){
        const int brow = ct*16 + lr;
        bf16x8 bfr = *(const bf16x8*)&Bs[(size_t)((brow << 4) + ((ks*4 + lq) ^ (brow & 7)))*8];
        acc[ct] = __builtin_amdgcn_mfma_f32_16x16x32_bf16(afr, bfr, acc[ct], 0, 0, 0);
      }
    }
  }
#pragma unroll
  for (int ct = 0; ct < 4; ++ct){
    int j = j0 + ct*16 + lr;
    if (j < 208){
#pragma unroll
      for (int r = 0; r < 4; ++r){
        int m = m0 + wid*16 + lq*4 + r;
        lin_z[((size_t)z*512 + m)*208 + j] = acc[ct][r];
      }
    }
  }
}

// ============ phase: quad-per-row coalesced loads (64B/quad), 1024 threads ============
__global__ __launch_bounds__(1024, 2) void phase_kernel(const float* __restrict__ lin_z,
                                                        const float* __restrict__ bo,
                                                        const float* __restrict__ Gr,
                                                        const float* __restrict__ Gi,
                                                        const float* __restrict__ hrr,
                                                        const float* __restrict__ hri,
                                                        float* __restrict__ accum)
{
  const int b = blockIdx.x;
  const int tid = threadIdx.x;
  __shared__ float psum[4][200];
  __shared__ float lsh[200];
  __shared__ float u[100];
  __shared__ float pq[100];
  __shared__ float wred[16];

  if (tid < 800){
    int zq = tid / 200, j = tid - zq*200;
    int z0 = (zq == 0) ? 0 : (6*zq + 1);
    int zn = (zq == 0) ? 7 : 6;
    float a = 0.f;
    for (int z = z0; z < z0 + zn; ++z)
      a += lin_z[((size_t)z*512 + b)*208 + j];
    psum[zq][j] = a;
  }
  __syncthreads();
  if (tid < 200)
    lsh[tid] = bo[tid] + psum[0][tid] + psum[1][tid] + psum[2][tid] + psum[3][tid];
  __syncthreads();
  if (tid < 100){
    float c = cosf(lsh[tid]);
    float s = sinf(lsh[100 + tid]);
    float hr = hrr[b*100 + tid];
    float hi = hri[b*100 + tid];
    u[tid]  = c*hr - s*hi;
    pq[tid] = c*hi + s*hr;
  }
  __syncthreads();

  const int m = tid >> 2, q = tid & 3;
  const float4* grow  = (const float4*)(Gr + ((size_t)b*256 + m)*100);
  const float4* girow = (const float4*)(Gi + ((size_t)b*256 + m)*100);
  float tr = 0.f, ti = 0.f;
#pragma unroll
  for (int k = 0; k < 6; ++k){
    int i = q + 4*k;
    float4 g  = grow[i];
    float4 gg = girow[i];
    float4 uu = *(const float4*)&u[i*4];
    float4 qq = *(const float4*)&pq[i*4];
    tr += g.x*uu.x - gg.x*qq.x;  ti += g.x*qq.x + gg.x*uu.x;
    tr += g.y*uu.y - gg.y*qq.y;  ti += g.y*qq.y + gg.y*uu.y;
    tr += g.z*uu.z - gg.z*qq.z;  ti += g.z*qq.z + gg.z*uu.z;
    tr += g.w*uu.w - gg.w*qq.w;  ti += g.w*qq.w + gg.w*uu.w;
  }
  if (q == 0){
    float4 g  = grow[24];
    float4 gg = girow[24];
    float4 uu = *(const float4*)&u[96];
    float4 qq = *(const float4*)&pq[96];
    tr += g.x*uu.x - gg.x*qq.x;  ti += g.x*qq.x + gg.x*uu.x;
    tr += g.y*uu.y - gg.y*qq.y;  ti += g.y*qq.y + gg.y*uu.y;
    tr += g.z*uu.z - gg.z*qq.z;  ti += g.z*qq.z + gg.z*uu.z;
    tr += g.w*uu.w - gg.w*qq.w;  ti += g.w*qq.w + gg.w*uu.w;
  }
  tr += __shfl_xor(tr, 1); tr += __shfl_xor(tr, 2);
  ti += __shfl_xor(ti, 1); ti += __shfl_xor(ti, 2);
  float ns = (q == 0) ? (tr*tr + ti*ti) : 0.f;
#pragma unroll
  for (int off = 4; off < 64; off <<= 1) ns += __shfl_down(ns, off);
  if ((tid & 63) == 0) wred[tid >> 6] = ns;
  __syncthreads();
  if (tid == 0){
    float t = 0.f;
#pragma unroll
    for (int w = 0; w < 16; ++w) t += wred[w];
    atomicAdd(accum, t);
  }
}

__global__ void finalize_kernel(const float* __restrict__ accum, float* __restrict__ out)
{
  out[0] = -accum[0] * (1.0f / 512.0f);
}

extern "C" void kernel_launch(void* const* d_in, const int* in_sizes, int n_in,
                              void* d_out, int out_size, void* d_ws, size_t ws_size,
                              hipStream_t stream)
{
  const float* F   = (const float*)d_in[0];
  const float* Gr  = (const float*)d_in[1];
  const float* Gi  = (const float*)d_in[2];
  const float* hrr = (const float*)d_in[3];
  const float* hri = (const float*)d_in[4];
  const float* W1  = (const float*)d_in[5];
  const float* b1  = (const float*)d_in[6];
  const float* g1  = (const float*)d_in[7];
  const float* be1 = (const float*)d_in[8];
  const float* W2  = (const float*)d_in[9];
  const float* b2  = (const float*)d_in[10];
  const float* g2  = (const float*)d_in[11];
  const float* be2 = (const float*)d_in[12];
  const float* W3  = (const float*)d_in[13];
  const float* b3  = (const float*)d_in[14];
  const float* g3  = (const float*)d_in[15];
  const float* be3 = (const float*)d_in[16];
  const float* W4  = (const float*)d_in[17];
  const float* b4  = (const float*)d_in[18];
  const float* g4  = (const float*)d_in[19];
  const float* be4 = (const float*)d_in[20];
  const float* Wo  = (const float*)d_in[21];
  const float* bo  = (const float*)d_in[22];

  char* ws = (char*)d_ws;
  unsigned short* y1   = (unsigned short*)(ws);
  unsigned short* y2   = (unsigned short*)(ws + 52428800);
  unsigned short* y3   = (unsigned short*)(ws);
  unsigned short* y4   = (unsigned short*)(ws + 52428800);
  unsigned short* Wob  = (unsigned short*)(ws + 65536000);   // aliases y2 tail: write AFTER conv3
  float*          lin_z= (float*)(ws + 13107200);            // aliases y1/y3: write after conv4
  float* stats = (float*)(ws + 78643200);                    // 2304 f32
  float* accum = (float*)(ws + 78656512);                    // 16 B
  unsigned short* Wpk1 = (unsigned short*)(ws + 78656528);
  unsigned short* Wpk2 = (unsigned short*)(ws + 78664720);
  unsigned short* Wpk3 = (unsigned short*)(ws + 78812176);
  unsigned short* Wpk4 = (unsigned short*)(ws + 78885904);

  hipMemsetAsync(ws + 78643200, 0, 13328, stream);   // stats + accum

  // merged weight packs (Wpk buffers live outside all activation regions)
  prep_kernel<<<65, 256, 0, stream>>>(W1, W2, W3, W4, Wpk1, Wpk2, Wpk3, Wpk4);

  conv1_mfma<<<512, 256, 0, stream>>>(F, Wpk1, b1, y1, stats);

  conv_mfma<128, 64><<<512, 512, 0, stream>>>(y1, stats,        g1, be1, Wpk2, b2, y2, stats + 1024);
  conv_mfma<64, 64><<<512, 512, 0, stream>>>( y2, stats + 1024, g2, be2, Wpk3, b3, y3, stats + 1536);

  // y2 is dead now -> safe to write Wob (aliases y2's tail region)
  wopack_kernel<<<256, 256, 0, stream>>>(Wo, Wob);

  conv_mfma<64, 32><<<512, 512, 0, stream>>>( y3, stats + 1536, g3, be3, Wpk4, b4, y4, stats + 2048);

  linear_mfma<<<dim3(8, 4, 25), 256, 0, stream>>>(y4, stats + 2048, g4, be4, Wob, lin_z);

  phase_kernel<<<512, 1024, 0, stream>>>(lin_z, bo, Gr, Gi, hrr, hri, accum);
  finalize_kernel<<<1, 1, 0, stream>>>(accum, (float*)d_out);
}